// Round 2
// 613.985 us; speedup vs baseline: 1.4282x; 1.4282x over previous
//
#include <hip/hip_runtime.h>

#define NMAT 1000
#define SA_PAD 68        // fp32 LDS row stride (16B-aligned rows, 2-way max bank conflict)
#define LDM 72           // bf16 LDS row stride for MFMA tiles (144 B = 9*16 B, 16B-aligned rows)

typedef short short8 __attribute__((ext_vector_type(8)));    // 8 x bf16 payload for MFMA operands
typedef float floatx4 __attribute__((ext_vector_type(4)));   // MFMA accumulator
typedef unsigned short ushortx4 __attribute__((ext_vector_type(4)));

__device__ __forceinline__ unsigned short f2bf(float f) {
    // fp32 -> bf16 round-to-nearest-even
    unsigned int u = __float_as_uint(f);
    u += 0x7fffu + ((u >> 16) & 1u);
    return (unsigned short)(u >> 16);
}

// 64x64x64 fp32 MAC core over LDS operands (row stride SA_PAD).
// 256 threads; each accumulates a 4x4 tile at (r0, c0).
__device__ __forceinline__ void mm_core(const float* __restrict__ sA,
                                        const float* __restrict__ sB,
                                        int r0, int c0, float acc[4][4])
{
#pragma unroll
    for (int k = 0; k < 64; k += 4) {
        float4 b0 = *(const float4*)&sB[(k + 0) * SA_PAD + c0];
        float4 b1 = *(const float4*)&sB[(k + 1) * SA_PAD + c0];
        float4 b2 = *(const float4*)&sB[(k + 2) * SA_PAD + c0];
        float4 b3 = *(const float4*)&sB[(k + 3) * SA_PAD + c0];
#pragma unroll
        for (int u = 0; u < 4; ++u) {
            float4 a = *(const float4*)&sA[(r0 + u) * SA_PAD + k];
            acc[u][0] += a.x * b0.x + a.y * b1.x + a.z * b2.x + a.w * b3.x;
            acc[u][1] += a.x * b0.y + a.y * b1.y + a.z * b2.y + a.w * b3.y;
            acc[u][2] += a.x * b0.z + a.y * b1.z + a.z * b2.z + a.w * b3.z;
            acc[u][3] += a.x * b0.w + a.y * b1.w + a.z * b2.w + a.w * b3.w;
        }
    }
}

// Vectorized global(64x64 fp32, stride 64) -> LDS(stride SA_PAD) copy; 4 float4 per thread.
__device__ __forceinline__ void stageLDS(float* __restrict__ s, const float* __restrict__ g, int tid)
{
#pragma unroll
    for (int q = 0; q < 4; ++q) {
        int i4 = tid + 256 * q;                 // 0..1023 float4 chunks
        int r = i4 >> 4, c4 = (i4 & 15) * 4;
        *(float4*)&s[r * SA_PAD + c4] = *(const float4*)&g[i4 * 4];
    }
}

// Kernel 1 (1 block): M = expm(K) (degree-12 Taylor, Paterson-Stockmeyer) with ALL
// intermediates LDS-resident, then seed tab[2^k] = M^(2^k), k=0..9, by repeated squaring.
// tab[i] = ws + i*4096 (fp32). Nothing outside tab[0..999] is ever written.
__global__ __launch_bounds__(256) void k_build(const float* __restrict__ K,
                                               float* __restrict__ ws)
{
    __shared__ __align__(16) float smem[6 * 64 * SA_PAD];   // 104,448 B (gfx950: 160 KB/CU)
    float* tab = ws;
    const int tid = threadIdx.x;

    // load K -> buf0; write tab[0] = I
#pragma unroll
    for (int q = 0; q < 4; ++q) {
        int i4 = tid + 256 * q;
        int r = i4 >> 4, c4 = (i4 & 15) * 4;
        *(float4*)&smem[r * SA_PAD + c4] = *(const float4*)&K[i4 * 4];
        float4 id = {0.f, 0.f, 0.f, 0.f};
        if (r >= c4 && r < c4 + 4) ((float*)&id)[r - c4] = 1.f;
        *(float4*)&tab[r * 64 + c4] = id;
    }

    const float c1_ = 1.f, c2_ = 0.5f, c3_ = 1.f / 6.f, c4_ = 1.f / 24.f, c5_ = 1.f / 120.f,
                c6_ = 1.f / 720.f, c7_ = 1.f / 5040.f, c8_ = 1.f / 40320.f, c9_ = 1.f / 362880.f,
                c10_ = 1.f / 3628800.f, c11_ = 1.f / 39916800.f, c12_ = 1.f / 479001600.f;

    // bufs: 0:K->M4->M256  1:T2->M8->M512  2:T3->M16  3:T4->M32  4:P1->M->M64  5:P2->M2->M128
    // ops : T2  T3  T4  P2  M   M2  M4  M8  M16 M32 M64 M128 M256 M512
    const signed char SD[14]  = {1, 2, 3, 5, 4, 5, 0, 1, 2, 3, 4, 5, 0, 1};
    const signed char SAi[14] = {0, 1, 1, 4, 5, 4, 5, 0, 1, 2, 3, 4, 5, 0};
    const signed char SBi[14] = {0, 0, 1, 3, 3, 4, 5, 0, 1, 2, 3, 4, 5, 0};
    const signed char SE[14]  = {-1, -1, -1, 0, 1, -1, -1, -1, -1, -1, -1, -1, -1, -1};
    const short       STt[14] = {-1, -1, -1, -1, 1, 2, 4, 8, 16, 32, 64, 128, 256, 512};

    const int r0 = (tid >> 4) * 4, c0 = (tid & 15) * 4;

#pragma unroll 1
    for (int st = 0; st < 14; ++st) {
        if (st == 3) {
            // P1 = c12*T4 + c8*I + c9*K + c10*T2 + c11*T3  -> buf4
            __syncthreads();
#pragma unroll
            for (int s = 0; s < 16; ++s) {
                int idx = tid + 256 * s;
                int r = idx >> 6, c = idx & 63;
                smem[4 * (64 * SA_PAD) + r * SA_PAD + c] =
                      c12_ * smem[3 * (64 * SA_PAD) + r * SA_PAD + c] + (r == c ? c8_ : 0.f)
                    + c9_  * smem[0 * (64 * SA_PAD) + r * SA_PAD + c]
                    + c10_ * smem[1 * (64 * SA_PAD) + r * SA_PAD + c]
                    + c11_ * smem[2 * (64 * SA_PAD) + r * SA_PAD + c];
            }
        }
        __syncthreads();   // prev-step writes visible; prev-step reads complete
        const float* A = smem + (int)SAi[st] * (64 * SA_PAD);
        const float* B = smem + (int)SBi[st] * (64 * SA_PAD);
        float acc[4][4] = {};
        mm_core(A, B, r0, c0, acc);

        float cI = 0.f, cK = 0.f, cT2 = 0.f, cT3 = 0.f;
        const int epi = SE[st];
        if (epi == 0) { cI = c4_; cK = c5_; cT2 = c6_; cT3 = c7_; }
        if (epi == 1) { cI = 1.f; cK = c1_; cT2 = c2_; cT3 = c3_; }

        float* D = smem + (int)SD[st] * (64 * SA_PAD);
        float* tp = (STt[st] >= 0) ? (tab + (size_t)STt[st] * 4096) : nullptr;
#pragma unroll
        for (int u = 0; u < 4; ++u) {
            int r = r0 + u;
            float o[4];
#pragma unroll
            for (int v = 0; v < 4; ++v) {
                int c = c0 + v;
                float val = acc[u][v];
                if (epi >= 0) {
                    val += (r == c ? cI : 0.f)
                         + cK  * smem[0 * (64 * SA_PAD) + r * SA_PAD + c]
                         + cT2 * smem[1 * (64 * SA_PAD) + r * SA_PAD + c]
                         + cT3 * smem[2 * (64 * SA_PAD) + r * SA_PAD + c];
                }
                o[v] = val;
            }
            float4 vv = {o[0], o[1], o[2], o[3]};
            *(float4*)&D[r * SA_PAD + c0] = vv;
            if (tp) *(float4*)&tp[r * 64 + c0] = vv;
        }
    }
}

// Kernel 2: block t computes tab[t] = product of seeds M^(2^k) over set bits of t (MSB-first).
// Seeds commute (all powers of one M), blocks fully independent -> one launch replaces
// the 8 serial doubling rounds.
__global__ __launch_bounds__(256) void k_pows(float* __restrict__ ws)
{
    __shared__ __align__(16) float s0[64 * SA_PAD], s1[64 * SA_PAD], s2[64 * SA_PAD];
    const int t = blockIdx.x;
    if (__popc(t) < 2) return;          // 0, 1, and powers of two already seeded
    float* tab = ws;
    const int tid = threadIdx.x;
    const int r0 = (tid >> 4) * 4, c0 = (tid & 15) * 4;

    float* P = s0;      // running product
    float* Bs = s1;     // next seed operand
    float* Cs = s2;     // product destination (swapped with P)

    int hb = 31 - __clz(t);
    stageLDS(P, tab + (size_t)(1 << hb) * 4096, tid);
    int rem = t & ~(1 << hb);

    while (rem) {
        int b = 31 - __clz(rem);
        rem &= ~(1 << b);
        stageLDS(Bs, tab + (size_t)(1 << b) * 4096, tid);
        __syncthreads();                // P and Bs staged
        float acc[4][4] = {};
        mm_core(P, Bs, r0, c0, acc);
        if (rem) {
#pragma unroll
            for (int u = 0; u < 4; ++u) {
                float4 vv = {acc[u][0], acc[u][1], acc[u][2], acc[u][3]};
                *(float4*)&Cs[(r0 + u) * SA_PAD + c0] = vv;
            }
        } else {
            float* C = tab + (size_t)t * 4096;
#pragma unroll
            for (int u = 0; u < 4; ++u) {
                float4 vv = {acc[u][0], acc[u][1], acc[u][2], acc[u][3]};
                *(float4*)&C[(r0 + u) * 64 + c0] = vv;
            }
        }
        __syncthreads();                // all reads of P/Bs done before reuse
        if (rem) { float* tmp = P; P = Cs; Cs = tmp; }
    }
}

// Kernel 3: y[b,t,:] = M^t * x0[b]. Block = (t, 128-row b-tile). bf16 MFMA 16x16x32, fp32 accum.
// x0 is read straight from the fp32 input (t=0 slice, 256 KB total -> L2-resident).
__global__ __launch_bounds__(256) void k_out(const float* __restrict__ in,
                                             const float* __restrict__ ws,
                                             float* __restrict__ out)
{
    __shared__ __align__(16) unsigned short lM[64 * LDM];    // M_t, row-major [i][j], bf16
    __shared__ __align__(16) unsigned short lX[128 * LDM];   // x0 tile, [b_local][j], bf16

    const int bx = blockIdx.x;
    const int t = bx >> 3;
    const int b0 = (bx & 7) * 128;
    const float* Mt = ws + (size_t)t * 4096;
    const int tid = threadIdx.x;

    // stage M_t (fp32 -> bf16), vectorized: 4 float4 loads + 4 ushort4 stores per thread
#pragma unroll
    for (int q = 0; q < 4; ++q) {
        int i4 = tid + 256 * q;                 // 1024 float4 chunks
        int i = i4 >> 4, c4 = (i4 & 15) * 4;
        float4 v = *(const float4*)&Mt[i4 * 4];
        ushortx4 h = { f2bf(v.x), f2bf(v.y), f2bf(v.z), f2bf(v.w) };
        *(ushortx4*)&lM[i * LDM + c4] = h;
    }
    // stage x0 tile (fp32 -> bf16), vectorized: 8 float4 loads + 8 ushort4 stores per thread
#pragma unroll
    for (int q = 0; q < 8; ++q) {
        int i4 = tid + 256 * q;                 // 2048 float4 chunks of 8192 floats
        int bb = i4 >> 4, c4 = (i4 & 15) * 4;
        float4 v = *(const float4*)&in[(size_t)(b0 + bb) * 64000 + c4];   // t=0 slice
        ushortx4 h = { f2bf(v.x), f2bf(v.y), f2bf(v.z), f2bf(v.w) };
        *(ushortx4*)&lX[bb * LDM + c4] = h;
    }
    __syncthreads();

    const int lane = tid & 63;
    const int w = tid >> 6;         // wave id 0..3
    const int m = lane & 15;        // A/B fragment row index within 16
    const int kg = lane >> 4;       // k-octet group 0..3 (also C/D row quad)

#pragma unroll
    for (int mt = 0; mt < 2; ++mt) {
        const int mtile = w * 2 + mt;    // 0..7 -> b rows [mtile*16, +16)
        short8 a0 = *(const short8*)&lX[(mtile * 16 + m) * LDM + kg * 8];        // k 0..31
        short8 a1 = *(const short8*)&lX[(mtile * 16 + m) * LDM + 32 + kg * 8];   // k 32..63
#pragma unroll
        for (int n = 0; n < 4; ++n) {    // output i-tile
            short8 bf0 = *(const short8*)&lM[(n * 16 + m) * LDM + kg * 8];
            short8 bf1 = *(const short8*)&lM[(n * 16 + m) * LDM + 32 + kg * 8];
            floatx4 acc = {0.f, 0.f, 0.f, 0.f};
            acc = __builtin_amdgcn_mfma_f32_16x16x32_bf16(a0, bf0, acc, 0, 0, 0);
            acc = __builtin_amdgcn_mfma_f32_16x16x32_bf16(a1, bf1, acc, 0, 0, 0);
            // C/D layout: col = lane&15 (= i within tile), row = kg*4 + v (= b within mtile)
            size_t base = (size_t)(b0 + mtile * 16 + kg * 4) * 64000 + (size_t)t * 64 + n * 16 + m;
            out[base + 0 * 64000] = acc[0];
            out[base + 1 * 64000] = acc[1];
            out[base + 2 * 64000] = acc[2];
            out[base + 3 * 64000] = acc[3];
        }
    }
}

extern "C" void kernel_launch(void* const* d_in, const int* in_sizes, int n_in,
                              void* d_out, int out_size, void* d_ws, size_t ws_size,
                              hipStream_t stream)
{
    const float* inp = (const float*)d_in[0];   // (1024, 1000, 64) fp32
    const float* K   = (const float*)d_in[1];   // (64, 64) fp32
    float* out = (float*)d_out;                 // (1024, 1000, 64) fp32
    float* ws  = (float*)d_ws;                  // tab: 1000 * 4096 fp32 = 16,384,000 B

    // 1) expm + power-of-two seeds (single block, all-LDS)
    hipLaunchKernelGGL(k_build, dim3(1), dim3(256), 0, stream, K, ws);
    // 2) all remaining powers in ONE launch via binary decomposition of t
    hipLaunchKernelGGL(k_pows, dim3(NMAT), dim3(256), 0, stream, ws);
    // 3) output GEMM
    hipLaunchKernelGGL(k_out, dim3(8000), dim3(256), 0, stream, inp, ws, out);
}

// Round 3
// 590.776 us; speedup vs baseline: 1.4843x; 1.0393x over previous
//
#include <hip/hip_runtime.h>

#define NMAT 1000
#define SA_PAD 68        // fp32 LDS row stride (16B-aligned rows, 2-way max bank conflict)
#define LDM 72           // bf16 LDS row stride for MFMA tiles (144 B rows, 2-way max conflict)

// ws layout (bytes):
//   [0,         8,192,000)  tab16: bf16[1000][64][64]   (row-major M^t, consumed by k_out)
//   [8,192,000, 8,355,840)  seedF: fp32[10][64][64]     (M^(2^k), k=0..9, consumed by k_pows)
//   [8,355,840, 8,486,912)  x0b  : bf16[1024][64]       (x0 slice, consumed by k_out)
// Max offset 8.5 MB, well inside the proven >=16.38 MB workspace.
#define SEEDF_OFF 2048000          // float offset of seedF
#define X0B_OFF   8355840          // byte offset of x0b

typedef short short8 __attribute__((ext_vector_type(8)));    // 8 x bf16 payload for MFMA operands
typedef float floatx4 __attribute__((ext_vector_type(4)));   // MFMA accumulator
typedef unsigned short ushortx4 __attribute__((ext_vector_type(4)));

__device__ __forceinline__ unsigned short f2bf(float f) {
    // fp32 -> bf16 round-to-nearest-even
    unsigned int u = __float_as_uint(f);
    u += 0x7fffu + ((u >> 16) & 1u);
    return (unsigned short)(u >> 16);
}

// 64x64x64 fp32 MAC core over LDS operands (row stride SA_PAD).
// 256 threads; each accumulates a 4x4 tile at (r0, c0).
__device__ __forceinline__ void mm_core(const float* __restrict__ sA,
                                        const float* __restrict__ sB,
                                        int r0, int c0, float acc[4][4])
{
#pragma unroll
    for (int k = 0; k < 64; k += 4) {
        float4 b0 = *(const float4*)&sB[(k + 0) * SA_PAD + c0];
        float4 b1 = *(const float4*)&sB[(k + 1) * SA_PAD + c0];
        float4 b2 = *(const float4*)&sB[(k + 2) * SA_PAD + c0];
        float4 b3 = *(const float4*)&sB[(k + 3) * SA_PAD + c0];
#pragma unroll
        for (int u = 0; u < 4; ++u) {
            float4 a = *(const float4*)&sA[(r0 + u) * SA_PAD + k];
            acc[u][0] += a.x * b0.x + a.y * b1.x + a.z * b2.x + a.w * b3.x;
            acc[u][1] += a.x * b0.y + a.y * b1.y + a.z * b2.y + a.w * b3.y;
            acc[u][2] += a.x * b0.z + a.y * b1.z + a.z * b2.z + a.w * b3.z;
            acc[u][3] += a.x * b0.w + a.y * b1.w + a.z * b2.w + a.w * b3.w;
        }
    }
}

// Vectorized global(64x64 fp32, stride 64) -> LDS(stride SA_PAD) copy; 4 float4 per thread.
__device__ __forceinline__ void stageLDS(float* __restrict__ s, const float* __restrict__ g, int tid)
{
#pragma unroll
    for (int q = 0; q < 4; ++q) {
        int i4 = tid + 256 * q;                 // 0..1023 float4 chunks
        int r = i4 >> 4, c4 = (i4 & 15) * 4;
        *(float4*)&s[r * SA_PAD + c4] = *(const float4*)&g[i4 * 4];
    }
}

// Kernel 1: block 0 computes M = expm(K) (degree-12 Taylor, Paterson-Stockmeyer) all-LDS,
// then seeds M^(2^k), k=0..9 (fp32 -> seedF, bf16 -> tab16). Blocks 1..16 convert x0 to bf16
// concurrently (independent work on otherwise-idle CUs).
__global__ __launch_bounds__(256) void k_build(const float* __restrict__ K,
                                               const float* __restrict__ in,
                                               float* __restrict__ ws)
{
    const int tid = threadIdx.x;
    unsigned short* tab16 = (unsigned short*)ws;
    unsigned short* x0b = (unsigned short*)((char*)ws + X0B_OFF);

    if (blockIdx.x != 0) {
        // x0 bf16 conversion: 64 batch-rows per block
        const int rb = (blockIdx.x - 1) * 64;
#pragma unroll
        for (int q = 0; q < 4; ++q) {
            int i4 = tid + 256 * q;             // 1024 float4 chunks of 4096 floats
            int b = rb + (i4 >> 4), c4 = (i4 & 15) * 4;
            float4 v = *(const float4*)&in[(size_t)b * 64000 + c4];   // t=0 slice
            ushortx4 h = { f2bf(v.x), f2bf(v.y), f2bf(v.z), f2bf(v.w) };
            *(ushortx4*)&x0b[(size_t)b * 64 + c4] = h;
        }
        return;
    }

    // ---- block 0: expm chain ----
    __shared__ __align__(16) float smem[6 * 64 * SA_PAD];   // 104,448 B

    // load K -> buf0; write tab16[0] = I (bf16)
#pragma unroll
    for (int q = 0; q < 4; ++q) {
        int i4 = tid + 256 * q;
        int r = i4 >> 4, c4 = (i4 & 15) * 4;
        *(float4*)&smem[r * SA_PAD + c4] = *(const float4*)&K[i4 * 4];
        ushortx4 id = {0, 0, 0, 0};
        if (r >= c4 && r < c4 + 4) ((unsigned short*)&id)[r - c4] = 0x3F80;  // bf16(1.0)
        *(ushortx4*)&tab16[r * 64 + c4] = id;
    }

    const float c1_ = 1.f, c2_ = 0.5f, c3_ = 1.f / 6.f, c4_ = 1.f / 24.f, c5_ = 1.f / 120.f,
                c6_ = 1.f / 720.f, c7_ = 1.f / 5040.f, c8_ = 1.f / 40320.f, c9_ = 1.f / 362880.f,
                c10_ = 1.f / 3628800.f, c11_ = 1.f / 39916800.f, c12_ = 1.f / 479001600.f;

    // bufs: 0:K->M4->M256  1:T2->M8->M512  2:T3->M16  3:T4->M32  4:P1->M->M64  5:P2->M2->M128
    // ops : T2  T3  T4  P2  M   M2  M4  M8  M16 M32 M64 M128 M256 M512
    const signed char SD[14]  = {1, 2, 3, 5, 4, 5, 0, 1, 2, 3, 4, 5, 0, 1};
    const signed char SAi[14] = {0, 1, 1, 4, 5, 4, 5, 0, 1, 2, 3, 4, 5, 0};
    const signed char SBi[14] = {0, 0, 1, 3, 3, 4, 5, 0, 1, 2, 3, 4, 5, 0};
    const signed char SE[14]  = {-1, -1, -1, 0, 1, -1, -1, -1, -1, -1, -1, -1, -1, -1};
    const short       STt[14] = {-1, -1, -1, -1, 1, 2, 4, 8, 16, 32, 64, 128, 256, 512};

    const int r0 = (tid >> 4) * 4, c0 = (tid & 15) * 4;

#pragma unroll 1
    for (int st = 0; st < 14; ++st) {
        if (st == 3) {
            // P1 = c12*T4 + c8*I + c9*K + c10*T2 + c11*T3  -> buf4
            __syncthreads();
#pragma unroll
            for (int s = 0; s < 16; ++s) {
                int idx = tid + 256 * s;
                int r = idx >> 6, c = idx & 63;
                smem[4 * (64 * SA_PAD) + r * SA_PAD + c] =
                      c12_ * smem[3 * (64 * SA_PAD) + r * SA_PAD + c] + (r == c ? c8_ : 0.f)
                    + c9_  * smem[0 * (64 * SA_PAD) + r * SA_PAD + c]
                    + c10_ * smem[1 * (64 * SA_PAD) + r * SA_PAD + c]
                    + c11_ * smem[2 * (64 * SA_PAD) + r * SA_PAD + c];
            }
        }
        __syncthreads();   // prev-step writes visible; prev-step reads complete
        const float* A = smem + (int)SAi[st] * (64 * SA_PAD);
        const float* B = smem + (int)SBi[st] * (64 * SA_PAD);
        float acc[4][4] = {};
        mm_core(A, B, r0, c0, acc);

        float cI = 0.f, cK = 0.f, cT2 = 0.f, cT3 = 0.f;
        const int epi = SE[st];
        if (epi == 0) { cI = c4_; cK = c5_; cT2 = c6_; cT3 = c7_; }
        if (epi == 1) { cI = 1.f; cK = c1_; cT2 = c2_; cT3 = c3_; }

        float* D = smem + (int)SD[st] * (64 * SA_PAD);
        float* sf = (STt[st] >= 0) ? (ws + SEEDF_OFF + (size_t)(st - 4) * 4096) : nullptr;
        unsigned short* tb = (STt[st] >= 0) ? (tab16 + (size_t)STt[st] * 4096) : nullptr;
#pragma unroll
        for (int u = 0; u < 4; ++u) {
            int r = r0 + u;
            float o[4];
#pragma unroll
            for (int v = 0; v < 4; ++v) {
                int c = c0 + v;
                float val = acc[u][v];
                if (epi >= 0) {
                    val += (r == c ? cI : 0.f)
                         + cK  * smem[0 * (64 * SA_PAD) + r * SA_PAD + c]
                         + cT2 * smem[1 * (64 * SA_PAD) + r * SA_PAD + c]
                         + cT3 * smem[2 * (64 * SA_PAD) + r * SA_PAD + c];
                }
                o[v] = val;
            }
            float4 vv = {o[0], o[1], o[2], o[3]};
            *(float4*)&D[r * SA_PAD + c0] = vv;
            if (sf) {
                *(float4*)&sf[r * 64 + c0] = vv;
                ushortx4 h = { f2bf(o[0]), f2bf(o[1]), f2bf(o[2]), f2bf(o[3]) };
                *(ushortx4*)&tb[r * 64 + c0] = h;
            }
        }
    }
}

// Kernel 2: block t computes tab16[t] = bf16( product of seeds M^(2^k) over set bits of t ).
// Chain stays fp32 in LDS; next seed is register-prefetched during the current matmul.
__global__ __launch_bounds__(256) void k_pows(float* __restrict__ ws)
{
    __shared__ __align__(16) float s0[64 * SA_PAD], s1[64 * SA_PAD], s2[64 * SA_PAD];
    const int t = blockIdx.x;
    if (__popc(t) < 2) return;          // 0, 1, and powers of two already seeded
    const float* seedF = ws + SEEDF_OFF;
    unsigned short* tab16 = (unsigned short*)ws;
    const int tid = threadIdx.x;
    const int r0 = (tid >> 4) * 4, c0 = (tid & 15) * 4;

    float* P = s0;      // running product
    float* Bs = s1;     // current seed operand
    float* Cs = s2;     // product destination (swapped with P)

    int hb = 31 - __clz(t);
    stageLDS(P, seedF + (size_t)hb * 4096, tid);
    int rem = t & ~(1 << hb);

    // preload first seed operand into registers
    float4 rg[4];
    {
        int b = 31 - __clz(rem);
        rem &= ~(1 << b);
        const float* g = seedF + (size_t)b * 4096;
#pragma unroll
        for (int q = 0; q < 4; ++q) rg[q] = *(const float4*)&g[(tid + 256 * q) * 4];
    }

    while (true) {
        __syncthreads();                // P staged/written; prior mm reads of Bs complete
        // commit prefetched seed to LDS
#pragma unroll
        for (int q = 0; q < 4; ++q) {
            int i4 = tid + 256 * q;
            int rr = i4 >> 4, c4 = (i4 & 15) * 4;
            *(float4*)&Bs[rr * SA_PAD + c4] = rg[q];
        }
        // prefetch next seed (overlaps with the matmul below)
        int nb = -1;
        if (rem) {
            nb = 31 - __clz(rem);
            rem &= ~(1 << nb);
            const float* g = seedF + (size_t)nb * 4096;
#pragma unroll
            for (int q = 0; q < 4; ++q) rg[q] = *(const float4*)&g[(tid + 256 * q) * 4];
        }
        __syncthreads();                // Bs visible
        float acc[4][4] = {};
        mm_core(P, Bs, r0, c0, acc);

        if (nb < 0) {                   // last product: store bf16 to table, done
            unsigned short* C = tab16 + (size_t)t * 4096;
#pragma unroll
            for (int u = 0; u < 4; ++u) {
                ushortx4 h = { f2bf(acc[u][0]), f2bf(acc[u][1]),
                               f2bf(acc[u][2]), f2bf(acc[u][3]) };
                *(ushortx4*)&C[(r0 + u) * 64 + c0] = h;
            }
            return;
        }
#pragma unroll
        for (int u = 0; u < 4; ++u) {
            float4 vv = {acc[u][0], acc[u][1], acc[u][2], acc[u][3]};
            *(float4*)&Cs[(r0 + u) * SA_PAD + c0] = vv;
        }
        float* tmp = P; P = Cs; Cs = tmp;   // loop-top sync publishes new P
    }
}

// Kernel 3: y[b,t,:] = M^t * x0[b]. Block = (t, 128-row b-tile). bf16 MFMA 16x16x32, fp32 accum.
// Both operands are pre-converted bf16 -> staging is a pure 16B/lane copy.
__global__ __launch_bounds__(256) void k_out(const float* __restrict__ ws,
                                             float* __restrict__ out)
{
    __shared__ __align__(16) unsigned short lM[64 * LDM];    // M_t, row-major [i][j], bf16
    __shared__ __align__(16) unsigned short lX[128 * LDM];   // x0 tile, [b_local][j], bf16

    const unsigned short* tab16 = (const unsigned short*)ws;
    const unsigned short* x0b = (const unsigned short*)((const char*)ws + X0B_OFF);

    const int bx = blockIdx.x;
    const int t = bx >> 3;
    const int b0 = (bx & 7) * 128;
    const unsigned short* Mt = tab16 + (size_t)t * 4096;
    const int tid = threadIdx.x;

    // stage M_t: 2 x 16B copies per thread
#pragma unroll
    for (int q = 0; q < 2; ++q) {
        int i8 = tid + 256 * q;                 // 512 ushort8 chunks
        int i = i8 >> 3, j8 = (i8 & 7) * 8;
        *(short8*)&lM[i * LDM + j8] = *(const short8*)&Mt[i8 * 8];
    }
    // stage x0 tile: 4 x 16B copies per thread
#pragma unroll
    for (int q = 0; q < 4; ++q) {
        int i8 = tid + 256 * q;                 // 1024 ushort8 chunks of 8192
        int bb = i8 >> 3, j8 = (i8 & 7) * 8;
        *(short8*)&lX[bb * LDM + j8] = *(const short8*)&x0b[(size_t)(b0 + bb) * 64 + j8];
    }
    __syncthreads();

    const int lane = tid & 63;
    const int w = tid >> 6;         // wave id 0..3
    const int m = lane & 15;        // A/B fragment row index within 16
    const int kg = lane >> 4;       // k-octet group 0..3 (also C/D row quad)

#pragma unroll
    for (int mt = 0; mt < 2; ++mt) {
        const int mtile = w * 2 + mt;    // 0..7 -> b rows [mtile*16, +16)
        short8 a0 = *(const short8*)&lX[(mtile * 16 + m) * LDM + kg * 8];        // k 0..31
        short8 a1 = *(const short8*)&lX[(mtile * 16 + m) * LDM + 32 + kg * 8];   // k 32..63
#pragma unroll
        for (int n = 0; n < 4; ++n) {    // output i-tile
            short8 bf0 = *(const short8*)&lM[(n * 16 + m) * LDM + kg * 8];
            short8 bf1 = *(const short8*)&lM[(n * 16 + m) * LDM + 32 + kg * 8];
            floatx4 acc = {0.f, 0.f, 0.f, 0.f};
            acc = __builtin_amdgcn_mfma_f32_16x16x32_bf16(a0, bf0, acc, 0, 0, 0);
            acc = __builtin_amdgcn_mfma_f32_16x16x32_bf16(a1, bf1, acc, 0, 0, 0);
            // C/D layout: col = lane&15 (= i within tile), row = kg*4 + v (= b within mtile)
            size_t base = (size_t)(b0 + mtile * 16 + kg * 4) * 64000 + (size_t)t * 64 + n * 16 + m;
            out[base + 0 * 64000] = acc[0];
            out[base + 1 * 64000] = acc[1];
            out[base + 2 * 64000] = acc[2];
            out[base + 3 * 64000] = acc[3];
        }
    }
}

extern "C" void kernel_launch(void* const* d_in, const int* in_sizes, int n_in,
                              void* d_out, int out_size, void* d_ws, size_t ws_size,
                              hipStream_t stream)
{
    const float* inp = (const float*)d_in[0];   // (1024, 1000, 64) fp32
    const float* K   = (const float*)d_in[1];   // (64, 64) fp32
    float* out = (float*)d_out;                 // (1024, 1000, 64) fp32
    float* ws  = (float*)d_ws;                  // uses first 8.5 MB (see layout above)

    // 1) expm + seeds (block 0) and x0 bf16 conversion (blocks 1..16), one launch
    hipLaunchKernelGGL(k_build, dim3(17), dim3(256), 0, stream, K, inp, ws);
    // 2) all remaining powers in ONE launch via binary decomposition of t
    hipLaunchKernelGGL(k_pows, dim3(NMAT), dim3(256), 0, stream, ws);
    // 3) output GEMM (pure bf16 staging)
    hipLaunchKernelGGL(k_out, dim3(8000), dim3(256), 0, stream, ws, out);
}